// Round 1
// baseline (362.750 us; speedup 1.0000x reference)
//
#include <hip/hip_runtime.h>
#include <cstdint>
#include <cstddef>

#define S_CELLS 4096   // 64*64
#define NB      8
#define NPTS    8192
#define E       128
#define MAXP    20
#define NHEADS  8

// ws layout:
//   counts: int[NB*S_CELLS]            @ 0          (131072 B)
//   slots:  int[NB*S_CELLS*MAXP]       @ 131072     (2621440 B)
//   A:      float[E*NHEADS]            @ 2752512    (4096 B)

// ---------------------------------------------------------------------------
// Kernel 1: per-point binning + x_grid passthrough copy.
// 65536 threads == b*n points == elements of x_grid (8*64*64*2). Fused.
// ---------------------------------------------------------------------------
__global__ void k_points(const float* __restrict__ x,
                         const float* __restrict__ x_grid,
                         int* __restrict__ counts,
                         int* __restrict__ slots,
                         float* __restrict__ out_xgrid) {
    int i = blockIdx.x * blockDim.x + threadIdx.x;   // 0..65535
    if (i >= NB * NPTS) return;

    // x_grid copy (same flat element count)
    out_xgrid[i] = x_grid[i];

    int b = i >> 13;                                  // / 8192
    float x0 = x[(size_t)i * 2 + 0];
    float x1 = x[(size_t)i * 2 + 1];
    // ref: t = (x-0)/(1-0)*(64-1); round = half-even -> rintf (RNE)
    float t0 = x0 * 63.0f;
    float t1 = x1 * 63.0f;
    int i0 = (int)rintf(t0);
    int i1 = (int)rintf(t1);
    i0 = min(max(i0, 0), 63);
    i1 = min(max(i1, 0), 63);
    int cell = b * S_CELLS + i0 * 64 + i1;
    int slot = atomicAdd(&counts[cell], 1);
    if (slot < MAXP) slots[cell * MAXP + slot] = i & (NPTS - 1);  // point idx within batch
}

// ---------------------------------------------------------------------------
// Kernel 2: precompute q = latent @ Wq, then A[i][h] = (Wk[i,h*16:+16]·q_h)/4
// One block, 128 threads.
// ---------------------------------------------------------------------------
__global__ void k_prep(const float* __restrict__ latent,
                       const float* __restrict__ Wq,
                       const float* __restrict__ Wk,
                       float* __restrict__ A) {
    __shared__ float lat[E];
    __shared__ float q[E];
    int j = threadIdx.x;
    lat[j] = latent[j];
    __syncthreads();
    float acc = 0.0f;
    for (int i = 0; i < E; ++i) acc += lat[i] * Wq[i * E + j];
    q[j] = acc;
    __syncthreads();
    // thread j == row i of A
    for (int h = 0; h < NHEADS; ++h) {
        float a = 0.0f;
        #pragma unroll
        for (int d = 0; d < 16; ++d) a += Wk[j * E + h * 16 + d] * q[h * 16 + d];
        A[j * NHEADS + h] = a * 0.25f;   // 1/sqrt(dh)=1/4 folded in
    }
}

// ---------------------------------------------------------------------------
// Kernel 3: one wave per cell. Gather tokens, scores via A, softmax,
// u_h = sum_t attn*kv_t, then out = u@Wv (per head), zg = out@Wo.
// Block = 256 threads = 4 waves = 4 cells.
// ---------------------------------------------------------------------------
__global__ void __launch_bounds__(256)
k_attn(const float* __restrict__ z,
       const float* __restrict__ z_grid,
       const int* __restrict__ counts,
       const int* __restrict__ slots,
       const float* __restrict__ A,
       const float* __restrict__ Wv,
       const float* __restrict__ Wo,
       float* __restrict__ zg) {
    __shared__ float tok_s[4][(MAXP + 1) * E];   // 43008 B
    __shared__ float u_t[4][E * 9];              // 18432 B (pad 9: conflict-free reads)
    __shared__ float out_l[4][E];                // 2048 B

    const int wv   = threadIdx.x >> 6;
    const int lane = threadIdx.x & 63;
    const int cell = blockIdx.x * 4 + wv;        // 0..32767
    const int cnt  = counts[cell];
    const int m    = min(cnt, MAXP);
    const int K    = m + 1;
    const int b    = cell >> 12;                 // / 4096

    float* tok = &tok_s[wv][0];

    // --- stage tokens into LDS (coalesced: 2 floats/lane per row) ---
    for (int t = 0; t < m; ++t) {
        int pt = slots[cell * MAXP + t];
        const float* src = z + ((size_t)(b * NPTS + pt)) * E;
        tok[t * E + lane]      = src[lane];
        tok[t * E + 64 + lane] = src[64 + lane];
    }
    {
        const float* src = z_grid + (size_t)cell * E;   // (b*4096+s)*128 == cell*128
        tok[m * E + lane]      = src[lane];
        tok[m * E + 64 + lane] = src[64 + lane];
    }
    __syncthreads();

    // --- per-lane A column: lane = (h, sg); covers i = sg + 8*ii (strided
    //     so tok LDS reads are bank-conflict-free broadcasts) ---
    const int h  = lane >> 3;   // 0..7
    const int sg = lane & 7;    // 0..7
    float Ac[16];
    #pragma unroll
    for (int ii = 0; ii < 16; ++ii) Ac[ii] = A[(sg + 8 * ii) * NHEADS + h];

    // --- pass 1: scores -> running max & sum (online, recompute in pass 2) ---
    float mx = -1e30f;
    float sum = 0.0f;
    for (int t = 0; t < K; ++t) {
        const float* tr = tok + t * E;
        float p = 0.0f;
        #pragma unroll
        for (int ii = 0; ii < 16; ++ii) p += tr[sg + 8 * ii] * Ac[ii];
        p += __shfl_xor(p, 1, 64);
        p += __shfl_xor(p, 2, 64);
        p += __shfl_xor(p, 4, 64);
        float nm = fmaxf(mx, p);
        sum = sum * __expf(mx - nm) + __expf(p - nm);
        mx = nm;
    }
    const float inv = 1.0f / sum;

    // --- pass 2: u[h][i] = sum_t attn_h(t) * tok[t][i] (i = sg+8*ii) ---
    float u[16];
    #pragma unroll
    for (int ii = 0; ii < 16; ++ii) u[ii] = 0.0f;
    for (int t = 0; t < K; ++t) {
        const float* tr = tok + t * E;
        float p = 0.0f;
        #pragma unroll
        for (int ii = 0; ii < 16; ++ii) p += tr[sg + 8 * ii] * Ac[ii];
        p += __shfl_xor(p, 1, 64);
        p += __shfl_xor(p, 2, 64);
        p += __shfl_xor(p, 4, 64);
        float a = __expf(p - mx) * inv;
        #pragma unroll
        for (int ii = 0; ii < 16; ++ii) u[ii] += a * tr[sg + 8 * ii];
    }
    // store transposed+padded: u_t[i*9 + h]
    #pragma unroll
    for (int ii = 0; ii < 16; ++ii) u_t[wv][(sg + 8 * ii) * 9 + h] = u[ii];
    __syncthreads();

    // --- stage 2: out[c] = sum_i u[h(c)][i] * Wv[i][c], c in {lane, lane+64} ---
    {
        const int h1 = lane >> 4;       // head of col c1=lane (0..3)
        const int h2 = h1 + 4;          // head of col c2=lane+64 (4..7)
        float o1 = 0.0f, o2 = 0.0f;
        #pragma unroll 4
        for (int i = 0; i < E; ++i) {
            float uv1 = u_t[wv][i * 9 + h1];
            float uv2 = u_t[wv][i * 9 + h2];
            o1 += uv1 * Wv[i * E + lane];
            o2 += uv2 * Wv[i * E + 64 + lane];
        }
        out_l[wv][lane]      = o1;
        out_l[wv][64 + lane] = o2;
    }
    __syncthreads();

    // --- stage 3: zg[cell][j] = sum_c out[c] * Wo[c][j] ---
    {
        float f1 = 0.0f, f2 = 0.0f;
        #pragma unroll 4
        for (int c = 0; c < E; ++c) {
            float oc = out_l[wv][c];    // broadcast read
            f1 += oc * Wo[c * E + lane];
            f2 += oc * Wo[c * E + 64 + lane];
        }
        float* dst = zg + (size_t)cell * E;
        dst[lane]      = f1;
        dst[64 + lane] = f2;
    }
}

// ---------------------------------------------------------------------------
extern "C" void kernel_launch(void* const* d_in, const int* in_sizes, int n_in,
                              void* d_out, int out_size, void* d_ws, size_t ws_size,
                              hipStream_t stream) {
    const float* x      = (const float*)d_in[0];
    const float* z      = (const float*)d_in[1];
    const float* x_grid = (const float*)d_in[2];
    const float* z_grid = (const float*)d_in[3];
    const float* latent = (const float*)d_in[4];
    const float* Wq     = (const float*)d_in[5];
    const float* Wk     = (const float*)d_in[6];
    const float* Wv     = (const float*)d_in[7];
    const float* Wo     = (const float*)d_in[8];
    // d_in[9] = max_patch (==20, hardcoded as MAXP)

    char* ws = (char*)d_ws;
    int*   counts = (int*)ws;
    int*   slots  = (int*)(ws + 131072);
    float* A      = (float*)(ws + 131072 + 2621440);

    float* out = (float*)d_out;

    hipMemsetAsync(counts, 0, NB * S_CELLS * sizeof(int), stream);

    k_points<<<(NB * NPTS) / 256, 256, 0, stream>>>(x, x_grid, counts, slots, out);
    k_prep<<<1, 128, 0, stream>>>(latent, Wq, Wk, A);
    k_attn<<<(NB * S_CELLS) / 4, 256, 0, stream>>>(z, z_grid, counts, slots, A,
                                                   Wv, Wo, out + NB * NPTS);
}

// Round 3
// 240.863 us; speedup vs baseline: 1.5060x; 1.5060x over previous
//
#include <hip/hip_runtime.h>
#include <hip/hip_bf16.h>
#include <cstdint>
#include <cstddef>

#define S_CELLS 4096   // 64*64
#define NB      8
#define NPTS    8192
#define E       128
#define MAXP    20
#define NHEADS  8
#define NPT_ROWS (NB * NPTS)          // 65536 point rows
#define NGR_ROWS (NB * S_CELLS)       // 32768 grid rows
#define NTOK     (NPT_ROWS + NGR_ROWS) // 98304 total token rows

// ws layout (bytes):
//   counts: int[NB*S_CELLS]                @ 0          (131072)
//   slots : int[NB*S_CELLS*MAXP]           @ 131072     (2621440)
//   A     : float[E*NHEADS]                @ 2752512    (4096)
//   SC    : float[NTOK*NHEADS]             @ 2756608    (3145728)
//   V     : bf16 [NTOK*E]                  @ 5902336    (25165824)
//   out   : float[NGR_ROWS*E]              @ 31068160   (16777216)
// total ~46 MB

__device__ __forceinline__ unsigned short f2bf_bits(float f) {
    unsigned u = __float_as_uint(f);
    unsigned rounded = u + 0x7FFFu + ((u >> 16) & 1u);   // RNE
    return (unsigned short)(rounded >> 16);
}
__device__ __forceinline__ float bf2f(unsigned short u) {
    return __uint_as_float(((unsigned)u) << 16);
}

// ---------------------------------------------------------------------------
// Kernel 1: per-point binning + x_grid passthrough copy (same element count).
// ---------------------------------------------------------------------------
__global__ void k_points(const float* __restrict__ x,
                         const float* __restrict__ x_grid,
                         int* __restrict__ counts,
                         int* __restrict__ slots,
                         float* __restrict__ out_xgrid) {
    int i = blockIdx.x * blockDim.x + threadIdx.x;   // 0..65535
    if (i >= NB * NPTS) return;
    out_xgrid[i] = x_grid[i];

    int b = i >> 13;
    float x0 = x[(size_t)i * 2 + 0];
    float x1 = x[(size_t)i * 2 + 1];
    int i0 = (int)rintf(x0 * 63.0f);   // RNE matches jnp.round
    int i1 = (int)rintf(x1 * 63.0f);
    i0 = min(max(i0, 0), 63);
    i1 = min(max(i1, 0), 63);
    int cell = b * S_CELLS + i0 * 64 + i1;
    int slot = atomicAdd(&counts[cell], 1);
    if (slot < MAXP) slots[cell * MAXP + slot] = i & (NPTS - 1);
}

// ---------------------------------------------------------------------------
// Kernel 2: q = latent @ Wq; A[i][h] = (Wk[i, h*16:+16] . q_h) / 4
// ---------------------------------------------------------------------------
__global__ void k_prep(const float* __restrict__ latent,
                       const float* __restrict__ Wq,
                       const float* __restrict__ Wk,
                       float* __restrict__ A) {
    __shared__ float lat[E];
    __shared__ float q[E];
    int j = threadIdx.x;
    lat[j] = latent[j];
    __syncthreads();
    float acc = 0.0f;
    for (int i = 0; i < E; ++i) acc += lat[i] * Wq[i * E + j];
    q[j] = acc;
    __syncthreads();
    for (int h = 0; h < NHEADS; ++h) {
        float a = 0.0f;
        #pragma unroll
        for (int d = 0; d < 16; ++d) a += Wk[j * E + h * 16 + d] * q[h * 16 + d];
        A[j * NHEADS + h] = a * 0.25f;
    }
}

// ---------------------------------------------------------------------------
// Kernel 3: tiled GEMM  C[N x 128] = X[N x 128] @ W[128 x 128]
//   - W cached in LDS as bf16 bits (transposed W_t[c][i]) -> fp32-accumulate
//   - X tile (32 rows) staged in LDS fp32, register-prefetched (grid-stride)
//   - thread tile: 8 rows x 2 cols
//   - optional fused SC[N x 8] = X @ A (token scores)
//   X rows < n1tiles*32 come from X1, the rest from X2 (concat source).
// LDS: 33792 + 16384 + 4224 = 54400 B -> 3 blocks/CU (12 waves/CU).
// ---------------------------------------------------------------------------
__device__ __forceinline__ void store_out(float* C, int idx, float v) { C[idx] = v; }
__device__ __forceinline__ void store_out(unsigned short* C, int idx, float v) {
    C[idx] = f2bf_bits(v);
}

template <typename OutT, bool WITH_SC>
__global__ void __launch_bounds__(256)
k_gemm(const float* __restrict__ X1, int n1tiles,
       const float* __restrict__ X2,
       const float* __restrict__ W,
       const float* __restrict__ Aw,
       OutT* __restrict__ C,
       float* __restrict__ SC,
       int ntiles) {
    __shared__ unsigned short W_t[E][132];   // bf16 bits, transposed: W_t[c][i]
    __shared__ float X_s[32 * E];            // 32-row fp32 tile
    __shared__ float A_t[NHEADS][132];       // A transposed (only used WITH_SC)

    const int t = threadIdx.x;

    // stage W (transpose + bf16 convert) — once per block
    for (int idx = t; idx < E * E; idx += 256) {
        int i = idx >> 7, c = idx & 127;
        W_t[c][i] = f2bf_bits(W[idx]);
    }
    if (WITH_SC) {
        for (int idx = t; idx < E * NHEADS; idx += 256) {
            int i = idx >> 3, h = idx & 7;
            A_t[h][i] = Aw[idx];
        }
    }

    const int c  = t & 63;       // col (and col+64)
    const int rg = t >> 6;       // row group: rows rg*8 .. rg*8+7

    int tile = blockIdx.x;
    float4 pf0, pf1, pf2, pf3;
    if (tile < ntiles) {
        const float* src = (tile < n1tiles) ? (X1 + (size_t)tile * 4096)
                                            : (X2 + (size_t)(tile - n1tiles) * 4096);
        const float4* s4 = (const float4*)src;
        pf0 = s4[t]; pf1 = s4[t + 256]; pf2 = s4[t + 512]; pf3 = s4[t + 768];
    }

    for (; tile < ntiles; tile += gridDim.x) {
        // publish prefetched tile
        {
            float4* x4 = (float4*)X_s;
            x4[t] = pf0; x4[t + 256] = pf1; x4[t + 512] = pf2; x4[t + 768] = pf3;
        }
        __syncthreads();   // X_s (and, first iter, W_t/A_t) ready

        int next = tile + gridDim.x;
        if (next < ntiles) {
            const float* src = (next < n1tiles) ? (X1 + (size_t)next * 4096)
                                                : (X2 + (size_t)(next - n1tiles) * 4096);
            const float4* s4 = (const float4*)src;
            pf0 = s4[t]; pf1 = s4[t + 256]; pf2 = s4[t + 512]; pf3 = s4[t + 768];
        }

        float acc0[8], acc1[8];
        #pragma unroll
        for (int r = 0; r < 8; ++r) { acc0[r] = 0.0f; acc1[r] = 0.0f; }

        #pragma unroll 8
        for (int ii = 0; ii < 32; ++ii) {
            const int i = ii * 4;
            ushort4 wa = *(const ushort4*)&W_t[c][i];
            ushort4 wb = *(const ushort4*)&W_t[c + 64][i];
            float wa0 = bf2f(wa.x), wa1 = bf2f(wa.y), wa2 = bf2f(wa.z), wa3 = bf2f(wa.w);
            float wb0 = bf2f(wb.x), wb1 = bf2f(wb.y), wb2 = bf2f(wb.z), wb3 = bf2f(wb.w);
            #pragma unroll
            for (int r = 0; r < 8; ++r) {
                float4 xv = *(const float4*)&X_s[(rg * 8 + r) * E + i];
                acc0[r] = fmaf(xv.x, wa0, acc0[r]);
                acc0[r] = fmaf(xv.y, wa1, acc0[r]);
                acc0[r] = fmaf(xv.z, wa2, acc0[r]);
                acc0[r] = fmaf(xv.w, wa3, acc0[r]);
                acc1[r] = fmaf(xv.x, wb0, acc1[r]);
                acc1[r] = fmaf(xv.y, wb1, acc1[r]);
                acc1[r] = fmaf(xv.z, wb2, acc1[r]);
                acc1[r] = fmaf(xv.w, wb3, acc1[r]);
            }
        }

        const int grow = tile * 32 + rg * 8;
        #pragma unroll
        for (int r = 0; r < 8; ++r) {
            store_out(C, (grow + r) * E + c,      acc0[r]);
            store_out(C, (grow + r) * E + c + 64, acc1[r]);
        }

        if (WITH_SC) {
            const int row = t >> 3, h = t & 7;
            float s = 0.0f;
            #pragma unroll 8
            for (int ii = 0; ii < 32; ++ii) {
                float4 xv = *(const float4*)&X_s[row * E + ii * 4];
                float4 av = *(const float4*)&A_t[h][ii * 4];
                s = fmaf(xv.x, av.x, s);
                s = fmaf(xv.y, av.y, s);
                s = fmaf(xv.z, av.z, s);
                s = fmaf(xv.w, av.w, s);
            }
            SC[(size_t)(tile * 32 + row) * NHEADS + h] = s;
        }
        __syncthreads();   // everyone done reading X_s before next overwrite
    }
}

// ---------------------------------------------------------------------------
// Kernel 4: light per-cell attention. One wave per cell, no LDS, no weights.
//   lane l owns output cols {l, l+64} (heads l>>4 and 4+(l>>4)).
//   Online softmax over K = m+1 tokens using precomputed SC and V.
// ---------------------------------------------------------------------------
__global__ void __launch_bounds__(256)
k_attn(const int* __restrict__ counts,
       const int* __restrict__ slots,
       const float* __restrict__ SC,
       const unsigned short* __restrict__ V,
       float* __restrict__ out) {
    const int wv   = threadIdx.x >> 6;
    const int lane = threadIdx.x & 63;
    const int cell = blockIdx.x * 4 + wv;      // 0..32767
    const int b    = cell >> 12;
    const int cnt  = counts[cell];
    const int m    = min(cnt, MAXP);

    const int h1 = lane >> 4;        // head of col lane
    const int h2 = 4 + h1;           // head of col lane+64

    int sl = (lane < m) ? slots[cell * MAXP + lane] : 0;

    // init with grid token
    size_t r0 = (size_t)(NPT_ROWS + cell);
    float m1 = SC[r0 * NHEADS + h1];
    float m2 = SC[r0 * NHEADS + h2];
    float s1 = 1.0f, s2 = 1.0f;
    float o1 = bf2f(V[r0 * E + lane]);
    float o2 = bf2f(V[r0 * E + 64 + lane]);

    for (int t = 0; t < m; ++t) {
        int pt = __shfl(sl, t, 64);
        size_t r = (size_t)(b * NPTS + pt);
        float a1 = SC[r * NHEADS + h1];
        float a2 = SC[r * NHEADS + h2];
        float v1 = bf2f(V[r * E + lane]);
        float v2 = bf2f(V[r * E + 64 + lane]);

        float nm1 = fmaxf(m1, a1);
        float e1  = __expf(a1 - nm1);
        float al1 = __expf(m1 - nm1);
        s1 = s1 * al1 + e1;
        o1 = o1 * al1 + e1 * v1;
        m1 = nm1;

        float nm2 = fmaxf(m2, a2);
        float e2  = __expf(a2 - nm2);
        float al2 = __expf(m2 - nm2);
        s2 = s2 * al2 + e2;
        o2 = o2 * al2 + e2 * v2;
        m2 = nm2;
    }

    out[(size_t)cell * E + lane]      = o1 / s1;
    out[(size_t)cell * E + 64 + lane] = o2 / s2;
}

// ---------------------------------------------------------------------------
extern "C" void kernel_launch(void* const* d_in, const int* in_sizes, int n_in,
                              void* d_out, int out_size, void* d_ws, size_t ws_size,
                              hipStream_t stream) {
    const float* x      = (const float*)d_in[0];
    const float* z      = (const float*)d_in[1];
    const float* x_grid = (const float*)d_in[2];
    const float* z_grid = (const float*)d_in[3];
    const float* latent = (const float*)d_in[4];
    const float* Wq     = (const float*)d_in[5];
    const float* Wk     = (const float*)d_in[6];
    const float* Wv     = (const float*)d_in[7];
    const float* Wo     = (const float*)d_in[8];

    char* ws = (char*)d_ws;
    int*            counts = (int*)(ws + 0);
    int*            slots  = (int*)(ws + 131072);
    float*          A      = (float*)(ws + 2752512);
    float*          SC     = (float*)(ws + 2756608);
    unsigned short* V      = (unsigned short*)(ws + 5902336);
    float*          outws  = (float*)(ws + 31068160);

    float* out_xgrid = (float*)d_out;                       // 65536 floats
    float* zg        = (float*)d_out + NB * NPTS;           // 32768*128 floats

    (void)hipMemsetAsync(counts, 0, NB * S_CELLS * sizeof(int), stream);

    k_points<<<(NB * NPTS) / 256, 256, 0, stream>>>(x, x_grid, counts, slots, out_xgrid);
    k_prep<<<1, 128, 0, stream>>>(latent, Wq, Wk, A);

    // V = [z; z_grid] @ Wv  and  SC = [z; z_grid] @ A
    // rows: 98304 -> 3072 tiles of 32; first 2048 tiles from z, rest from z_grid
    k_gemm<unsigned short, true><<<768, 256, 0, stream>>>(
        z, 2048, z_grid, Wv, A, V, SC, 3072);

    k_attn<<<(NB * S_CELLS) / 4, 256, 0, stream>>>(counts, slots, SC, V, outws);

    // zg = out @ Wo : 32768 rows -> 1024 tiles
    k_gemm<float, false><<<512, 256, 0, stream>>>(
        outws, 1024, nullptr, Wo, nullptr, zg, nullptr, 1024);
}

// Round 4
// 149.947 us; speedup vs baseline: 2.4192x; 1.6063x over previous
//
#include <hip/hip_runtime.h>
#include <hip/hip_bf16.h>
#include <cstdint>
#include <cstddef>

#define S_CELLS 4096   // 64*64
#define NB      8
#define NPTS    8192
#define E       128
#define MAXP    20
#define NHEADS  8
#define NPT_ROWS (NB * NPTS)           // 65536 point rows
#define NGR_ROWS (NB * S_CELLS)        // 32768 grid rows
#define NTOK     (NPT_ROWS + NGR_ROWS) // 98304 total token rows

// ws layout (bytes):
//   counts: int[NB*S_CELLS]                @ 0          (131072)
//   slots : int[NB*S_CELLS*MAXP]           @ 131072     (2621440)
//   A     : float[E*NHEADS]                @ 2752512    (4096)
//   SC    : float[NTOK*NHEADS]             @ 2756608    (3145728)
//   V     : bf16 [NTOK*E]                  @ 5902336    (25165824)
//   outb  : bf16 [NGR_ROWS*E]              @ 31068160   (8388608)

typedef __attribute__((ext_vector_type(8))) short bf16x8;
typedef __attribute__((ext_vector_type(4))) float f32x4;

__device__ __forceinline__ unsigned short f2bf_bits(float f) {
    unsigned u = __float_as_uint(f);
    unsigned rounded = u + 0x7FFFu + ((u >> 16) & 1u);   // RNE
    return (unsigned short)(rounded >> 16);
}
__device__ __forceinline__ float bf2f(unsigned short u) {
    return __uint_as_float(((unsigned)u) << 16);
}

// ---------------------------------------------------------------------------
// Kernel 1: per-point binning + x_grid passthrough copy (same element count).
// ---------------------------------------------------------------------------
__global__ void k_points(const float* __restrict__ x,
                         const float* __restrict__ x_grid,
                         int* __restrict__ counts,
                         int* __restrict__ slots,
                         float* __restrict__ out_xgrid) {
    int i = blockIdx.x * blockDim.x + threadIdx.x;   // 0..65535
    if (i >= NB * NPTS) return;
    out_xgrid[i] = x_grid[i];

    int b = i >> 13;
    float x0 = x[(size_t)i * 2 + 0];
    float x1 = x[(size_t)i * 2 + 1];
    int i0 = (int)rintf(x0 * 63.0f);   // RNE matches jnp.round
    int i1 = (int)rintf(x1 * 63.0f);
    i0 = min(max(i0, 0), 63);
    i1 = min(max(i1, 0), 63);
    int cell = b * S_CELLS + i0 * 64 + i1;
    int slot = atomicAdd(&counts[cell], 1);
    if (slot < MAXP) slots[cell * MAXP + slot] = i & (NPTS - 1);
}

// ---------------------------------------------------------------------------
// Kernel 2: q = latent @ Wq; A[i][h] = (Wk[i, h*16:+16] . q_h) / 4
// ---------------------------------------------------------------------------
__global__ void k_prep(const float* __restrict__ latent,
                       const float* __restrict__ Wq,
                       const float* __restrict__ Wk,
                       float* __restrict__ A) {
    __shared__ float lat[E];
    __shared__ float q[E];
    int j = threadIdx.x;
    lat[j] = latent[j];
    __syncthreads();
    float acc = 0.0f;
    for (int i = 0; i < E; ++i) acc += lat[i] * Wq[i * E + j];
    q[j] = acc;
    __syncthreads();
    for (int h = 0; h < NHEADS; ++h) {
        float a = 0.0f;
        #pragma unroll
        for (int d = 0; d < 16; ++d) a += Wk[j * E + h * 16 + d] * q[h * 16 + d];
        A[j * NHEADS + h] = a * 0.25f;
    }
}

// ---------------------------------------------------------------------------
// A-fragment loaders: lane (m = lane&15, q = lane>>4) needs
// X[row][kq*32 + q*8 + j], j=0..7 as bf16.
// ---------------------------------------------------------------------------
__device__ __forceinline__ bf16x8 load_afrag(const float* __restrict__ X,
                                             int row, int kq, int q) {
    const float4* xr = (const float4*)(X + (size_t)row * E);
    float4 lo = xr[kq * 8 + q * 2];
    float4 hi = xr[kq * 8 + q * 2 + 1];
    bf16x8 f;
    f[0] = (short)f2bf_bits(lo.x);
    f[1] = (short)f2bf_bits(lo.y);
    f[2] = (short)f2bf_bits(lo.z);
    f[3] = (short)f2bf_bits(lo.w);
    f[4] = (short)f2bf_bits(hi.x);
    f[5] = (short)f2bf_bits(hi.y);
    f[6] = (short)f2bf_bits(hi.z);
    f[7] = (short)f2bf_bits(hi.w);
    return f;
}
__device__ __forceinline__ bf16x8 load_afrag(const unsigned short* __restrict__ X,
                                             int row, int kq, int q) {
    return *(const bf16x8*)(X + (size_t)row * E + kq * 32 + q * 8);
}

__device__ __forceinline__ void store_out(float* C, size_t idx, float v) { C[idx] = v; }
__device__ __forceinline__ void store_out(unsigned short* C, size_t idx, float v) {
    C[idx] = f2bf_bits(v);
}

// ---------------------------------------------------------------------------
// Kernel 3: MFMA GEMM  C[N x 128] = X[N x 128] @ W[128 x 128]  (+ SC = X @ A)
//   - W staged once per block in LDS as bf16, transposed W_t[n][k], +8 pad
//     (A-score matrix occupies n-rows 128..135; rows 136..143 zeroed)
//   - X fragments loaded straight from global (each element used exactly once)
//   - 4 waves/block; wave computes MT*16 rows x 128 cols via 16x16x32 MFMA
//   - verified layouts: A m=lane&15,k=quad*8+j; B n=lane&15,k=quad*8+j;
//     C/D col=lane&15, row=quad*4+reg
// LDS: 144*136*2 = 39168 B -> 4 blocks/CU.
// ---------------------------------------------------------------------------
template <typename InT, typename OutT, bool WITH_SC, int MT>
__global__ void __launch_bounds__(256)
k_gemm_mfma(const InT* __restrict__ X1, int n1blocks,
            const InT* __restrict__ X2,
            const float* __restrict__ W,
            const float* __restrict__ Aw,
            OutT* __restrict__ C,
            float* __restrict__ SC) {
    __shared__ unsigned short W_t[144][136];

    const int t = threadIdx.x;

    for (int idx = t; idx < E * E; idx += 256) {
        int k = idx >> 7, n = idx & 127;
        W_t[n][k] = f2bf_bits(W[idx]);
    }
    if (WITH_SC) {
        for (int idx = t; idx < E * NHEADS; idx += 256) {
            int k = idx >> 3, h = idx & 7;
            W_t[128 + h][k] = f2bf_bits(Aw[idx]);
        }
        for (int idx = t; idx < 8 * 136; idx += 256) {
            int rr = idx / 136, cc = idx - rr * 136;
            W_t[136 + rr][cc] = 0;
        }
    }
    __syncthreads();

    const int lane = t & 63;
    const int wv   = t >> 6;
    const int cn   = lane & 15;   // n within tile / m within A-frag
    const int q    = lane >> 4;

    const int rows_per_block = 4 * MT * 16;
    const int grow0 = blockIdx.x * rows_per_block;          // global output row base
    const InT* Xsrc;
    int srow;                                               // row base within source
    if (blockIdx.x < n1blocks) { Xsrc = X1; srow = grow0; }
    else                       { Xsrc = X2; srow = grow0 - n1blocks * rows_per_block; }

    const int NT = WITH_SC ? 9 : 8;
    f32x4 acc[MT][9];
    #pragma unroll
    for (int mt = 0; mt < MT; ++mt)
        #pragma unroll
        for (int nt = 0; nt < 9; ++nt)
            acc[mt][nt] = f32x4{0.0f, 0.0f, 0.0f, 0.0f};

    #pragma unroll
    for (int kq = 0; kq < 4; ++kq) {
        bf16x8 a[MT];
        #pragma unroll
        for (int mt = 0; mt < MT; ++mt)
            a[mt] = load_afrag(Xsrc, srow + wv * (MT * 16) + mt * 16 + cn, kq, q);
        #pragma unroll
        for (int nt = 0; nt < NT; ++nt) {
            const bf16x8 b = *(const bf16x8*)&W_t[nt * 16 + cn][kq * 32 + q * 8];
            #pragma unroll
            for (int mt = 0; mt < MT; ++mt)
                acc[mt][nt] = __builtin_amdgcn_mfma_f32_16x16x32_bf16(
                    a[mt], b, acc[mt][nt], 0, 0, 0);
        }
    }

    // epilogue: C/D layout col=cn, row=q*4+r
    #pragma unroll
    for (int mt = 0; mt < MT; ++mt) {
        const int rb = grow0 + wv * (MT * 16) + mt * 16 + q * 4;
        #pragma unroll
        for (int nt = 0; nt < 8; ++nt)
            #pragma unroll
            for (int r = 0; r < 4; ++r)
                store_out(C, (size_t)(rb + r) * E + nt * 16 + cn, acc[mt][nt][r]);
        if (WITH_SC && cn < 8) {
            #pragma unroll
            for (int r = 0; r < 4; ++r)
                SC[(size_t)(rb + r) * NHEADS + cn] = acc[mt][8][r];
        }
    }
}

// ---------------------------------------------------------------------------
// Kernel 4: light per-cell attention, unroll-4 with exact no-op masking.
//   lane l owns output cols {l, l+64} (heads l>>4 and 4+(l>>4)).
//   Masked token: score=-1e30 -> e=0, alpha=1 -> exact identity update.
// ---------------------------------------------------------------------------
__global__ void __launch_bounds__(256)
k_attn(const int* __restrict__ counts,
       const int* __restrict__ slots,
       const float* __restrict__ SC,
       const unsigned short* __restrict__ V,
       unsigned short* __restrict__ out) {
    const int wv   = threadIdx.x >> 6;
    const int lane = threadIdx.x & 63;
    const int cell = blockIdx.x * 4 + wv;      // 0..32767
    const int b    = cell >> 12;
    const int cnt  = counts[cell];
    const int m    = min(cnt, MAXP);

    const int h1 = lane >> 4;        // head of col lane
    const int h2 = 4 + h1;           // head of col lane+64

    int sl = (lane < m) ? slots[cell * MAXP + lane] : 0;

    // init with grid token
    size_t r0 = (size_t)(NPT_ROWS + cell);
    float m1 = SC[r0 * NHEADS + h1];
    float m2 = SC[r0 * NHEADS + h2];
    float s1 = 1.0f, s2 = 1.0f;
    float o1 = bf2f(V[r0 * E + lane]);
    float o2 = bf2f(V[r0 * E + 64 + lane]);

    const int base = b * NPTS;

    for (int t0 = 0; t0 < m; t0 += 4) {
        float a1v[4], a2v[4], v1v[4], v2v[4];
        #pragma unroll
        for (int j = 0; j < 4; ++j) {
            int pt = __shfl(sl, t0 + j, 64);
            size_t r = (size_t)(base + pt);
            bool val = (t0 + j) < m;
            float sa1 = SC[r * NHEADS + h1];
            float sa2 = SC[r * NHEADS + h2];
            a1v[j] = val ? sa1 : -1e30f;
            a2v[j] = val ? sa2 : -1e30f;
            v1v[j] = bf2f(V[r * E + lane]);
            v2v[j] = bf2f(V[r * E + 64 + lane]);
        }
        #pragma unroll
        for (int j = 0; j < 4; ++j) {
            float nm1 = fmaxf(m1, a1v[j]);
            float e1  = __expf(a1v[j] - nm1);
            float al1 = __expf(m1 - nm1);
            s1 = s1 * al1 + e1;
            o1 = o1 * al1 + e1 * v1v[j];
            m1 = nm1;

            float nm2 = fmaxf(m2, a2v[j]);
            float e2  = __expf(a2v[j] - nm2);
            float al2 = __expf(m2 - nm2);
            s2 = s2 * al2 + e2;
            o2 = o2 * al2 + e2 * v2v[j];
            m2 = nm2;
        }
    }

    out[(size_t)cell * E + lane]      = f2bf_bits(o1 / s1);
    out[(size_t)cell * E + 64 + lane] = f2bf_bits(o2 / s2);
}

// ---------------------------------------------------------------------------
extern "C" void kernel_launch(void* const* d_in, const int* in_sizes, int n_in,
                              void* d_out, int out_size, void* d_ws, size_t ws_size,
                              hipStream_t stream) {
    const float* x      = (const float*)d_in[0];
    const float* z      = (const float*)d_in[1];
    const float* x_grid = (const float*)d_in[2];
    const float* z_grid = (const float*)d_in[3];
    const float* latent = (const float*)d_in[4];
    const float* Wq     = (const float*)d_in[5];
    const float* Wk     = (const float*)d_in[6];
    const float* Wv     = (const float*)d_in[7];
    const float* Wo     = (const float*)d_in[8];

    char* ws = (char*)d_ws;
    int*            counts = (int*)(ws + 0);
    int*            slots  = (int*)(ws + 131072);
    float*          A      = (float*)(ws + 2752512);
    float*          SC     = (float*)(ws + 2756608);
    unsigned short* V      = (unsigned short*)(ws + 5902336);
    unsigned short* outb   = (unsigned short*)(ws + 31068160);

    float* out_xgrid = (float*)d_out;                       // 65536 floats
    float* zg        = (float*)d_out + NB * NPTS;           // 32768*128 floats

    (void)hipMemsetAsync(counts, 0, NB * S_CELLS * sizeof(int), stream);

    k_points<<<(NB * NPTS) / 256, 256, 0, stream>>>(x, x_grid, counts, slots, out_xgrid);
    k_prep<<<1, 128, 0, stream>>>(latent, Wq, Wk, A);

    // V = [z; z_grid] @ Wv  and  SC = [z; z_grid] @ A
    // 98304 rows -> 768 blocks of 128 rows; first 512 blocks from z
    k_gemm_mfma<float, unsigned short, true, 2><<<768, 256, 0, stream>>>(
        z, 512, z_grid, Wv, A, V, SC);

    k_attn<<<(NB * S_CELLS) / 4, 256, 0, stream>>>(counts, slots, SC, V, outb);

    // zg = outb @ Wo : 32768 rows -> 512 blocks of 64 rows (MT=1)
    k_gemm_mfma<unsigned short, float, false, 1><<<512, 256, 0, stream>>>(
        outb, 512, nullptr, Wo, nullptr, zg, nullptr);
}

// Round 5
// 148.449 us; speedup vs baseline: 2.4436x; 1.0101x over previous
//
#include <hip/hip_runtime.h>
#include <hip/hip_bf16.h>
#include <cstdint>
#include <cstddef>

#define S_CELLS 4096   // 64*64
#define NB      8
#define NPTS    8192
#define E       128
#define MAXP    20
#define NHEADS  8
#define NPT_ROWS (NB * NPTS)           // 65536 point rows
#define NGR_ROWS (NB * S_CELLS)        // 32768 grid rows
#define NTOK     (NPT_ROWS + NGR_ROWS) // 98304 total token rows

// ws layout (bytes):
//   counts: int[NB*S_CELLS]                @ 0          (131072)
//   slots : int[NB*S_CELLS*MAXP]           @ 131072     (2621440)
//   A     : float[E*NHEADS]                @ 2752512    (4096)
//   SC    : float[NTOK*NHEADS]             @ 2756608    (3145728)
//   V     : bf16 [NTOK*E]                  @ 5902336    (25165824)

typedef __attribute__((ext_vector_type(8))) short bf16x8;
typedef __attribute__((ext_vector_type(4))) float f32x4;
typedef __attribute__((ext_vector_type(4))) unsigned short us4;

__device__ __forceinline__ unsigned short f2bf_bits(float f) {
    unsigned u = __float_as_uint(f);
    unsigned rounded = u + 0x7FFFu + ((u >> 16) & 1u);   // RNE
    return (unsigned short)(rounded >> 16);
}
__device__ __forceinline__ float bf2f(unsigned short u) {
    return __uint_as_float(((unsigned)u) << 16);
}

// ---------------------------------------------------------------------------
// Stage W[128x128] (row-major, k-major) -> LDS bf16 transposed W_t[n][k].
// Per item: 4 coalesced global loads (consecutive n across lanes) + one
// 8B-aligned ds_write_b64 (row stride 136 shorts = 272 B, 272%8==0).
// ---------------------------------------------------------------------------
__device__ __forceinline__ void stage_w_t(const float* __restrict__ W,
                                          unsigned short (*__restrict__ W_t)[136],
                                          int t) {
    #pragma unroll
    for (int it = 0; it < 16; ++it) {
        int id = t + it * 256;      // 0..4095
        int n  = id & 127;
        int kc = id >> 7;           // 0..31, covers k = 4*kc..4*kc+3
        float w0 = W[(size_t)(4 * kc + 0) * E + n];
        float w1 = W[(size_t)(4 * kc + 1) * E + n];
        float w2 = W[(size_t)(4 * kc + 2) * E + n];
        float w3 = W[(size_t)(4 * kc + 3) * E + n];
        us4 v;
        v.x = f2bf_bits(w0); v.y = f2bf_bits(w1);
        v.z = f2bf_bits(w2); v.w = f2bf_bits(w3);
        *(us4*)&W_t[n][4 * kc] = v;
    }
}

// ---------------------------------------------------------------------------
// Kernel 1: per-point binning + x_grid copy; block 0 additionally computes
// q = latent @ Wq and A[i][h] = (Wk[i, h*16:+16] . q_h) / 4.
// Grid is exactly 256 blocks x 256 (covers 65536 points == x_grid elements).
// ---------------------------------------------------------------------------
__global__ void __launch_bounds__(256)
k_points(const float* __restrict__ x,
         const float* __restrict__ x_grid,
         const float* __restrict__ latent,
         const float* __restrict__ Wq,
         const float* __restrict__ Wk,
         int* __restrict__ counts,
         int* __restrict__ slots,
         float* __restrict__ A,
         float* __restrict__ out_xgrid) {
    int i = blockIdx.x * 256 + threadIdx.x;   // 0..65535
    out_xgrid[i] = x_grid[i];

    int b = i >> 13;
    float x0 = x[(size_t)i * 2 + 0];
    float x1 = x[(size_t)i * 2 + 1];
    int i0 = (int)rintf(x0 * 63.0f);   // RNE matches jnp.round
    int i1 = (int)rintf(x1 * 63.0f);
    i0 = min(max(i0, 0), 63);
    i1 = min(max(i1, 0), 63);
    int cell = b * S_CELLS + i0 * 64 + i1;
    int slot = atomicAdd(&counts[cell], 1);
    if (slot < MAXP) slots[cell * MAXP + slot] = i & (NPTS - 1);

    if (blockIdx.x == 0) {
        __shared__ float lat[E];
        __shared__ float qv[E];
        const int t = threadIdx.x;
        const int j = t & 127;
        if (t < E) lat[t] = latent[t];
        __syncthreads();
        // both halves compute identical q[j]; duplicate same-value write is benign
        float acc = 0.0f;
        for (int k2 = 0; k2 < E; ++k2) acc += lat[k2] * Wq[k2 * E + j];
        qv[j] = acc;
        __syncthreads();
        const int hb = (t >> 7) * 4;            // 4 heads per half
        for (int h = hb; h < hb + 4; ++h) {
            float a = 0.0f;
            #pragma unroll
            for (int d = 0; d < 16; ++d) a += Wk[j * E + h * 16 + d] * qv[h * 16 + d];
            A[j * NHEADS + h] = a * 0.25f;
        }
    }
}

// ---------------------------------------------------------------------------
// Kernel 2: MFMA GEMM  V = [z; z_grid] @ Wv (bf16 out) + SC = [z; z_grid] @ A
//   - Wv in LDS bf16 transposed (n rows 0..127); A occupies n-rows 128..135,
//     rows 136..143 zeroed. X fragments straight from global (used once).
//   - 4 waves x MT=2: block = 128 rows. 768 blocks (first 512 read z).
//   - layouts (HW-verified): A-frag m=lane&15,k=q*8+j (k-quad kq*32);
//     B-frag n=lane&15 same k; C/D col=lane&15, row=q*4+r.
// LDS: 144*136*2 = 39168 B -> 4 blocks/CU.
// ---------------------------------------------------------------------------
__device__ __forceinline__ bf16x8 load_afrag_f32(const float* __restrict__ X,
                                                 int row, int kq, int q) {
    const float4* xr = (const float4*)(X + (size_t)row * E);
    float4 lo = xr[kq * 8 + q * 2];
    float4 hi = xr[kq * 8 + q * 2 + 1];
    bf16x8 f;
    f[0] = (short)f2bf_bits(lo.x);
    f[1] = (short)f2bf_bits(lo.y);
    f[2] = (short)f2bf_bits(lo.z);
    f[3] = (short)f2bf_bits(lo.w);
    f[4] = (short)f2bf_bits(hi.x);
    f[5] = (short)f2bf_bits(hi.y);
    f[6] = (short)f2bf_bits(hi.z);
    f[7] = (short)f2bf_bits(hi.w);
    return f;
}

__global__ void __launch_bounds__(256)
k_gemm1(const float* __restrict__ Xz,
        const float* __restrict__ Xg,
        const float* __restrict__ Wv,
        const float* __restrict__ Aw,
        unsigned short* __restrict__ V,
        float* __restrict__ SC) {
    __shared__ unsigned short W_t[144][136];

    const int t = threadIdx.x;
    stage_w_t(Wv, W_t, t);
    for (int idx = t; idx < E * NHEADS; idx += 256) {
        int k = idx >> 3, hh = idx & 7;
        W_t[128 + hh][k] = f2bf_bits(Aw[idx]);
    }
    for (int idx = t; idx < 8 * 136; idx += 256) {
        int rr = idx / 136, cc = idx - rr * 136;
        W_t[136 + rr][cc] = 0;
    }
    __syncthreads();

    const int lane = t & 63;
    const int wv   = t >> 6;
    const int cn   = lane & 15;
    const int q    = lane >> 4;

    const int grow0 = blockIdx.x * 128;
    const float* Xsrc;
    int srow;
    if (blockIdx.x < 512) { Xsrc = Xz; srow = grow0; }
    else                  { Xsrc = Xg; srow = grow0 - 65536; }

    f32x4 acc[2][9];
    #pragma unroll
    for (int mt = 0; mt < 2; ++mt)
        #pragma unroll
        for (int nt = 0; nt < 9; ++nt)
            acc[mt][nt] = f32x4{0.0f, 0.0f, 0.0f, 0.0f};

    #pragma unroll
    for (int kq = 0; kq < 4; ++kq) {
        bf16x8 a[2];
        #pragma unroll
        for (int mt = 0; mt < 2; ++mt)
            a[mt] = load_afrag_f32(Xsrc, srow + wv * 32 + mt * 16 + cn, kq, q);
        #pragma unroll
        for (int nt = 0; nt < 9; ++nt) {
            const bf16x8 b = *(const bf16x8*)&W_t[nt * 16 + cn][kq * 32 + q * 8];
            #pragma unroll
            for (int mt = 0; mt < 2; ++mt)
                acc[mt][nt] = __builtin_amdgcn_mfma_f32_16x16x32_bf16(
                    a[mt], b, acc[mt][nt], 0, 0, 0);
        }
    }

    #pragma unroll
    for (int mt = 0; mt < 2; ++mt) {
        const int rb = grow0 + wv * 32 + mt * 16 + q * 4;
        #pragma unroll
        for (int nt = 0; nt < 8; ++nt)
            #pragma unroll
            for (int r = 0; r < 4; ++r)
                V[(size_t)(rb + r) * E + nt * 16 + cn] = f2bf_bits(acc[mt][nt][r]);
        if (cn < 8) {
            #pragma unroll
            for (int r = 0; r < 4; ++r)
                SC[(size_t)(rb + r) * NHEADS + cn] = acc[mt][8][r];
        }
    }
}

// ---------------------------------------------------------------------------
// Kernel 3: fused attention + Wo projection.
//   Block = 64 cells (all same batch: 64 blocks/batch). 4 waves.
//   Phase 1: wave wv handles cells wv*16..wv*16+15. Lane owns cols {2l,2l+1}
//     (one head h=l>>3 -> single softmax state, packed uint V loads).
//     Result -> LDS X_s bf16 (A-fragment-ready layout).
//   Phase 2: wave computes its 16 rows x 128 cols via MFMA with LDS Wo.
// LDS: 128*136*2 + 64*136*2 = 52224 B -> 3 blocks/CU.
// ---------------------------------------------------------------------------
__global__ void __launch_bounds__(256)
k_attn_proj(const int* __restrict__ counts,
            const int* __restrict__ slots,
            const float* __restrict__ SC,
            const unsigned short* __restrict__ V,
            const float* __restrict__ Wo,
            float* __restrict__ zg) {
    __shared__ unsigned short W_t[128][136];
    __shared__ unsigned short X_s[64][136];

    const int t = threadIdx.x;
    stage_w_t(Wo, W_t, t);

    const int lane = t & 63;
    const int wv   = t >> 6;
    const int cell_base = blockIdx.x * 64 + wv * 16;
    const int b    = blockIdx.x >> 6;          // 64 blocks per batch
    const int base = b * NPTS;
    const int h    = lane >> 3;

    int cnt_all = (lane < 16) ? counts[cell_base + lane] : 0;
    int slw     = (lane < MAXP) ? slots[(size_t)cell_base * MAXP + lane] : 0;

    for (int ci = 0; ci < 16; ++ci) {
        const int cell = cell_base + ci;
        const int m = min(__shfl(cnt_all, ci, 64), MAXP);
        int slw_n = 0;
        if (ci < 15)
            slw_n = (lane < MAXP) ? slots[(size_t)(cell + 1) * MAXP + lane] : 0;

        size_t r0 = (size_t)(NPT_ROWS + cell);
        float mm = SC[r0 * NHEADS + h];
        float ss = 1.0f;
        unsigned v0 = *(const unsigned*)(V + r0 * E + 2 * lane);
        float o0 = bf2f((unsigned short)v0);
        float o1 = bf2f((unsigned short)(v0 >> 16));

        for (int t0 = 0; t0 < m; t0 += 4) {
            float av[4], p0[4], p1[4];
            #pragma unroll
            for (int j = 0; j < 4; ++j) {
                int pt = __shfl(slw, t0 + j, 64);
                bool val = (t0 + j) < m;
                pt = val ? pt : 0;              // clamp (slots beyond m are garbage)
                size_t r = (size_t)(base + pt);
                float sa = SC[r * NHEADS + h];
                av[j] = val ? sa : -1e30f;      // masked -> e=0, alpha=1: exact no-op
                unsigned vv = *(const unsigned*)(V + r * E + 2 * lane);
                p0[j] = bf2f((unsigned short)vv);
                p1[j] = bf2f((unsigned short)(vv >> 16));
            }
            #pragma unroll
            for (int j = 0; j < 4; ++j) {
                float nm = fmaxf(mm, av[j]);
                float e  = __expf(av[j] - nm);
                float al = __expf(mm - nm);
                ss = ss * al + e;
                o0 = o0 * al + e * p0[j];
                o1 = o1 * al + e * p1[j];
                mm = nm;
            }
        }
        float inv = 1.0f / ss;
        unsigned packed = (unsigned)f2bf_bits(o0 * inv)
                        | ((unsigned)f2bf_bits(o1 * inv) << 16);
        *(unsigned*)&X_s[wv * 16 + ci][2 * lane] = packed;
        slw = slw_n;
    }
    __syncthreads();

    // Phase 2: rows wv*16 + (0..15) @ Wo
    const int cn = lane & 15;
    const int q  = lane >> 4;
    f32x4 acc[8];
    #pragma unroll
    for (int nt = 0; nt < 8; ++nt) acc[nt] = f32x4{0.0f, 0.0f, 0.0f, 0.0f};

    #pragma unroll
    for (int kq = 0; kq < 4; ++kq) {
        bf16x8 a = *(const bf16x8*)&X_s[wv * 16 + cn][kq * 32 + q * 8];
        #pragma unroll
        for (int nt = 0; nt < 8; ++nt) {
            const bf16x8 bb = *(const bf16x8*)&W_t[nt * 16 + cn][kq * 32 + q * 8];
            acc[nt] = __builtin_amdgcn_mfma_f32_16x16x32_bf16(a, bb, acc[nt], 0, 0, 0);
        }
    }

    const int rb = blockIdx.x * 64 + wv * 16 + q * 4;
    #pragma unroll
    for (int nt = 0; nt < 8; ++nt)
        #pragma unroll
        for (int r = 0; r < 4; ++r)
            zg[(size_t)(rb + r) * E + nt * 16 + cn] = acc[nt][r];
}

// ---------------------------------------------------------------------------
extern "C" void kernel_launch(void* const* d_in, const int* in_sizes, int n_in,
                              void* d_out, int out_size, void* d_ws, size_t ws_size,
                              hipStream_t stream) {
    const float* x      = (const float*)d_in[0];
    const float* z      = (const float*)d_in[1];
    const float* x_grid = (const float*)d_in[2];
    const float* z_grid = (const float*)d_in[3];
    const float* latent = (const float*)d_in[4];
    const float* Wq     = (const float*)d_in[5];
    const float* Wk     = (const float*)d_in[6];
    const float* Wv     = (const float*)d_in[7];
    const float* Wo     = (const float*)d_in[8];

    char* ws = (char*)d_ws;
    int*            counts = (int*)(ws + 0);
    int*            slots  = (int*)(ws + 131072);
    float*          A      = (float*)(ws + 2752512);
    float*          SC     = (float*)(ws + 2756608);
    unsigned short* V      = (unsigned short*)(ws + 5902336);

    float* out_xgrid = (float*)d_out;                  // 65536 floats
    float* zg        = (float*)d_out + NB * NPTS;      // 32768*128 floats

    (void)hipMemsetAsync(counts, 0, NB * S_CELLS * sizeof(int), stream);

    k_points<<<256, 256, 0, stream>>>(x, x_grid, latent, Wq, Wk,
                                      counts, slots, A, out_xgrid);

    k_gemm1<<<768, 256, 0, stream>>>(z, z_grid, Wv, A, V, SC);

    k_attn_proj<<<512, 256, 0, stream>>>(counts, slots, SC, V, Wo, zg);
}

// Round 6
// 139.913 us; speedup vs baseline: 2.5927x; 1.0610x over previous
//
#include <hip/hip_runtime.h>
#include <cstdint>
#include <cstddef>

#define S_CELLS 4096   // 64*64
#define NB      8
#define NPTS    8192
#define E       128
#define MAXP    20
#define NHEADS  8
#define NPT_ROWS 65536
#define NGR_ROWS 32768

// ws layout (bytes):
//   counts: int[NB*S_CELLS]      @ 0         (131072)
//   slots : int[NB*S_CELLS*20]   @ 131072    (2621440)
//   WT1   : bf16 image 144x136   @ 2752512   (40960 incl. pad; 39168 used)
//   WT2   : bf16 image 128x136   @ 2793472   (34816)
//   SC    : float[98304*8]       @ 2828288   (3145728)
//   V     : bf16 [98304*128]     @ 5974016   (25165824)
#define WS_COUNTS 0
#define WS_SLOTS  131072
#define WS_WT1    2752512
#define WS_WT2    2793472
#define WS_SC     2828288
#define WS_V      5974016

typedef __attribute__((ext_vector_type(8))) short bf16x8;
typedef __attribute__((ext_vector_type(4))) float f32x4;

__device__ __forceinline__ unsigned short f2bf_bits(float f) {
    unsigned u = __float_as_uint(f);
    unsigned rounded = u + 0x7FFFu + ((u >> 16) & 1u);   // RNE
    return (unsigned short)(rounded >> 16);
}
__device__ __forceinline__ float bf2f(unsigned short u) {
    return __uint_as_float(((unsigned)u) << 16);
}

// ---------------------------------------------------------------------------
// Kernel 1 (grid 265):
//   blocks 0..255 : per-point binning + x_grid passthrough copy
//   block  256    : q = latent@Wq; A[i][h] = (Wk[i,h*16:+16].q_h)/4 -> WT1
//                   rows 128..135 (bf16); zero rows 136..143
//   blocks 257..260: Wv -> WT1 rows 0..127 (bf16, transposed [n][k], pad 136)
//   blocks 261..264: Wo -> WT2 (same layout)
// ---------------------------------------------------------------------------
__global__ void __launch_bounds__(256)
k_prep(const float* __restrict__ x,
       const float* __restrict__ x_grid,
       const float* __restrict__ latent,
       const float* __restrict__ Wq,
       const float* __restrict__ Wk,
       const float* __restrict__ Wv,
       const float* __restrict__ Wo,
       int* __restrict__ counts,
       int* __restrict__ slots,
       unsigned short* __restrict__ WT1,
       unsigned short* __restrict__ WT2,
       float* __restrict__ out_xgrid) {
    const int t   = threadIdx.x;
    const int blk = blockIdx.x;

    if (blk < 256) {                         // ---- binning + x_grid copy
        int i = blk * 256 + t;               // 0..65535
        out_xgrid[i] = x_grid[i];
        int b = i >> 13;
        float x0 = x[(size_t)i * 2 + 0];
        float x1 = x[(size_t)i * 2 + 1];
        int i0 = (int)rintf(x0 * 63.0f);     // RNE matches jnp.round
        int i1 = (int)rintf(x1 * 63.0f);
        i0 = min(max(i0, 0), 63);
        i1 = min(max(i1, 0), 63);
        int cell = b * S_CELLS + i0 * 64 + i1;
        int slot = atomicAdd(&counts[cell], 1);
        if (slot < MAXP) slots[(size_t)cell * MAXP + slot] = i & (NPTS - 1);
        return;
    }

    if (blk == 256) {                        // ---- q, A -> WT1 rows 128..143
        __shared__ float lat[E];
        __shared__ float qv[E];
        const int j = t & 127;
        if (t < E) lat[t] = latent[t];
        __syncthreads();
        float acc = 0.0f;                    // both halves compute identical q[j]
        for (int k2 = 0; k2 < E; ++k2) acc += lat[k2] * Wq[k2 * E + j];
        qv[j] = acc;
        __syncthreads();
        const int hb = (t >> 7) * 4;
        for (int h = hb; h < hb + 4; ++h) {
            float a = 0.0f;
            #pragma unroll
            for (int d = 0; d < 16; ++d) a += Wk[j * E + h * 16 + d] * qv[h * 16 + d];
            WT1[(size_t)(128 + h) * 136 + j] = f2bf_bits(a * 0.25f);
        }
        for (int idx = t; idx < 8 * 136; idx += 256) {   // zero rows 136..143
            int rr = idx / 136, cc = idx - rr * 136;
            WT1[(size_t)(136 + rr) * 136 + cc] = 0;
        }
        return;
    }

    // ---- weight conversion: transpose via LDS, coalesced in and out
    {
        const float* W = (blk < 261) ? Wv : Wo;
        unsigned short* WT = (blk < 261) ? WT1 : WT2;
        const int n0 = ((blk - 257) & 3) * 32;
        __shared__ float lbuf[128][33];
        #pragma unroll
        for (int it = 0; it < 16; ++it) {
            int k  = (t >> 5) + it * 8;      // 0..127
            int nl = t & 31;
            lbuf[k][nl] = W[(size_t)k * E + n0 + nl];
        }
        __syncthreads();
        for (int idx = t; idx < 32 * 136; idx += 256) {
            int nl = idx / 136, k = idx - nl * 136;
            float v = (k < 128) ? lbuf[k][nl] : 0.0f;
            WT[(size_t)(n0 + nl) * 136 + k] = f2bf_bits(v);
        }
    }
}

// ---------------------------------------------------------------------------
// Kernel 2: MFMA GEMM  V = [z; z_grid] @ Wv (bf16) + SC = [z; z_grid] @ A
//   WT1 image staged by linear float4 copy (no transpose, no conflicts).
//   4 waves x MT=2 -> 128 rows/block; 768 blocks (first 512 read z).
//   Layouts (HW-verified): A-frag m=lane&15, k=kq*32+q*8+j; B-frag n=lane&15
//   same k; C/D col=lane&15, row=q*4+r.
// LDS 40960 B -> 4 blocks/CU.
// ---------------------------------------------------------------------------
__device__ __forceinline__ bf16x8 load_afrag_f32(const float* __restrict__ X,
                                                 int row, int kq, int q) {
    const float4* xr = (const float4*)(X + (size_t)row * E);
    float4 lo = xr[kq * 8 + q * 2];
    float4 hi = xr[kq * 8 + q * 2 + 1];
    bf16x8 f;
    f[0] = (short)f2bf_bits(lo.x);
    f[1] = (short)f2bf_bits(lo.y);
    f[2] = (short)f2bf_bits(lo.z);
    f[3] = (short)f2bf_bits(lo.w);
    f[4] = (short)f2bf_bits(hi.x);
    f[5] = (short)f2bf_bits(hi.y);
    f[6] = (short)f2bf_bits(hi.z);
    f[7] = (short)f2bf_bits(hi.w);
    return f;
}

__global__ void __launch_bounds__(256)
k_gemm1(const float* __restrict__ Xz,
        const float* __restrict__ Xg,
        const unsigned short* __restrict__ WT1g,
        unsigned short* __restrict__ V,
        float* __restrict__ SC) {
    __shared__ unsigned short W_t[20480];    // 40960 B (144x136 + pad)

    const int t = threadIdx.x;
    {
        const float4* src = (const float4*)WT1g;
        float4* dst = (float4*)W_t;
        #pragma unroll
        for (int it = 0; it < 10; ++it) dst[t + it * 256] = src[t + it * 256];
    }
    __syncthreads();

    const int lane = t & 63;
    const int wv   = t >> 6;
    const int cn   = lane & 15;
    const int q    = lane >> 4;

    const int grow0 = blockIdx.x * 128;
    const float* Xsrc;
    int srow;
    if (blockIdx.x < 512) { Xsrc = Xz; srow = grow0; }
    else                  { Xsrc = Xg; srow = grow0 - NPT_ROWS; }

    f32x4 acc[2][9];
    #pragma unroll
    for (int mt = 0; mt < 2; ++mt)
        #pragma unroll
        for (int nt = 0; nt < 9; ++nt)
            acc[mt][nt] = f32x4{0.0f, 0.0f, 0.0f, 0.0f};

    #pragma unroll
    for (int kq = 0; kq < 4; ++kq) {
        bf16x8 a[2];
        #pragma unroll
        for (int mt = 0; mt < 2; ++mt)
            a[mt] = load_afrag_f32(Xsrc, srow + wv * 32 + mt * 16 + cn, kq, q);
        #pragma unroll
        for (int nt = 0; nt < 9; ++nt) {
            const bf16x8 b = *(const bf16x8*)&W_t[(size_t)(nt * 16 + cn) * 136 + kq * 32 + q * 8];
            #pragma unroll
            for (int mt = 0; mt < 2; ++mt)
                acc[mt][nt] = __builtin_amdgcn_mfma_f32_16x16x32_bf16(
                    a[mt], b, acc[mt][nt], 0, 0, 0);
        }
    }

    #pragma unroll
    for (int mt = 0; mt < 2; ++mt) {
        const int rb = grow0 + wv * 32 + mt * 16 + q * 4;
        #pragma unroll
        for (int nt = 0; nt < 8; ++nt)
            #pragma unroll
            for (int r = 0; r < 4; ++r)
                V[(size_t)(rb + r) * E + nt * 16 + cn] = f2bf_bits(acc[mt][nt][r]);
        if (cn < 8) {
            #pragma unroll
            for (int r = 0; r < 4; ++r)
                SC[(size_t)(rb + r) * NHEADS + cn] = acc[mt][8][r];
        }
    }
}

// ---------------------------------------------------------------------------
// Kernel 3: fused attention + Wo projection. Block = 16 cells (2048 blocks),
//   wave handles 4 cells (slots + grid-token prefetched for all 4 upfront).
//   Lane owns cols {2l,2l+1} (single head h=l>>3 -> one softmax state,
//   packed uint V loads). Results -> X_s bf16; phase 2: wave wv does
//   nt = {2wv, 2wv+1} via MFMA with LDS-staged WT2.
// LDS: 34816 + 4352 = 39168 B -> 4 blocks/CU.
// ---------------------------------------------------------------------------
__global__ void __launch_bounds__(256)
k_attn_proj(const int* __restrict__ counts,
            const int* __restrict__ slots,
            const float* __restrict__ SC,
            const unsigned short* __restrict__ Vg,
            const unsigned short* __restrict__ WT2g,
            float* __restrict__ zg) {
    __shared__ unsigned short W_t[17408];    // 34816 B (128x136)
    __shared__ unsigned short X_s[16][136];

    const int t = threadIdx.x;
    {   // linear stage of WT2 (2176 float4s)
        const float4* src = (const float4*)WT2g;
        float4* dst = (float4*)W_t;
        #pragma unroll
        for (int it = 0; it < 8; ++it) dst[t + it * 256] = src[t + it * 256];
        if (t < 128) dst[t + 2048] = src[t + 2048];
    }

    const int lane = t & 63;
    const int wv   = t >> 6;
    const int cb   = blockIdx.x * 16;        // block cell base
    const int cw   = cb + wv * 4;            // this wave's first cell
    const int b    = blockIdx.x >> 8;        // 256 blocks per batch
    const int base = b * NPTS;
    const int h    = lane >> 3;

    int cnt_l = (lane < 16) ? counts[cb + lane] : 0;

    int m4[4], sl[4];
    #pragma unroll
    for (int ci = 0; ci < 4; ++ci) {
        m4[ci] = min(__shfl(cnt_l, wv * 4 + ci, 64), MAXP);
        sl[ci] = (lane < MAXP) ? slots[(size_t)(cw + ci) * MAXP + lane] : 0;
    }

    // grid-token prefetch for all 4 cells
    float mm[4], ss[4], o0[4], o1[4];
    #pragma unroll
    for (int ci = 0; ci < 4; ++ci) {
        size_t r0 = (size_t)(NPT_ROWS + cw + ci);
        mm[ci] = SC[r0 * NHEADS + h];
        unsigned v0 = *(const unsigned*)(Vg + r0 * E + 2 * lane);
        o0[ci] = bf2f((unsigned short)v0);
        o1[ci] = bf2f((unsigned short)(v0 >> 16));
        ss[ci] = 1.0f;
    }

    #pragma unroll
    for (int ci = 0; ci < 4; ++ci) {
        const int m = m4[ci];
        for (int t0 = 0; t0 < m; t0 += 4) {
            float av[4], p0[4], p1[4];
            #pragma unroll
            for (int j = 0; j < 4; ++j) {
                int pt = __shfl(sl[ci], t0 + j, 64);
                bool val = (t0 + j) < m;
                pt = val ? pt : 0;           // slots beyond m are garbage
                size_t r = (size_t)(base + pt);
                float sa = SC[r * NHEADS + h];
                av[j] = val ? sa : -1e30f;   // masked -> e=0, alpha=1: exact no-op
                unsigned vv = *(const unsigned*)(Vg + r * E + 2 * lane);
                p0[j] = bf2f((unsigned short)vv);
                p1[j] = bf2f((unsigned short)(vv >> 16));
            }
            #pragma unroll
            for (int j = 0; j < 4; ++j) {
                float nm = fmaxf(mm[ci], av[j]);
                float e  = __expf(av[j] - nm);
                float al = __expf(mm[ci] - nm);
                ss[ci] = ss[ci] * al + e;
                o0[ci] = o0[ci] * al + e * p0[j];
                o1[ci] = o1[ci] * al + e * p1[j];
                mm[ci] = nm;
            }
        }
        float inv = 1.0f / ss[ci];
        unsigned packed = (unsigned)f2bf_bits(o0[ci] * inv)
                        | ((unsigned)f2bf_bits(o1[ci] * inv) << 16);
        *(unsigned*)&X_s[wv * 4 + ci][2 * lane] = packed;
    }
    __syncthreads();

    // Phase 2: 16 rows x 128 cols; wave wv covers cols [wv*32, wv*32+32)
    const int cn  = lane & 15;
    const int q   = lane >> 4;
    const int nt0 = wv * 2;
    f32x4 acc[2];
    acc[0] = f32x4{0.0f, 0.0f, 0.0f, 0.0f};
    acc[1] = f32x4{0.0f, 0.0f, 0.0f, 0.0f};

    #pragma unroll
    for (int kq = 0; kq < 4; ++kq) {
        bf16x8 a = *(const bf16x8*)&X_s[cn][kq * 32 + q * 8];
        #pragma unroll
        for (int j = 0; j < 2; ++j) {
            const bf16x8 bb = *(const bf16x8*)&W_t[(size_t)((nt0 + j) * 16 + cn) * 136 + kq * 32 + q * 8];
            acc[j] = __builtin_amdgcn_mfma_f32_16x16x32_bf16(a, bb, acc[j], 0, 0, 0);
        }
    }

    const int rb = blockIdx.x * 16 + q * 4;
    #pragma unroll
    for (int j = 0; j < 2; ++j)
        #pragma unroll
        for (int r = 0; r < 4; ++r)
            zg[(size_t)(rb + r) * E + (nt0 + j) * 16 + cn] = acc[j][r];
}

// ---------------------------------------------------------------------------
extern "C" void kernel_launch(void* const* d_in, const int* in_sizes, int n_in,
                              void* d_out, int out_size, void* d_ws, size_t ws_size,
                              hipStream_t stream) {
    const float* x      = (const float*)d_in[0];
    const float* z      = (const float*)d_in[1];
    const float* x_grid = (const float*)d_in[2];
    const float* z_grid = (const float*)d_in[3];
    const float* latent = (const float*)d_in[4];
    const float* Wq     = (const float*)d_in[5];
    const float* Wk     = (const float*)d_in[6];
    const float* Wv     = (const float*)d_in[7];
    const float* Wo     = (const float*)d_in[8];

    char* ws = (char*)d_ws;
    int*            counts = (int*)(ws + WS_COUNTS);
    int*            slots  = (int*)(ws + WS_SLOTS);
    unsigned short* WT1    = (unsigned short*)(ws + WS_WT1);
    unsigned short* WT2    = (unsigned short*)(ws + WS_WT2);
    float*          SC     = (float*)(ws + WS_SC);
    unsigned short* V      = (unsigned short*)(ws + WS_V);

    float* out_xgrid = (float*)d_out;                  // 65536 floats
    float* zg        = (float*)d_out + NB * NPTS;      // 32768*128 floats

    (void)hipMemsetAsync(counts, 0, NB * S_CELLS * sizeof(int), stream);

    k_prep<<<265, 256, 0, stream>>>(x, x_grid, latent, Wq, Wk, Wv, Wo,
                                    counts, slots, WT1, WT2, out_xgrid);

    k_gemm1<<<768, 256, 0, stream>>>(z, z_grid, WT1, V, SC);

    k_attn_proj<<<2048, 256, 0, stream>>>(counts, slots, SC, V, WT2, zg);
}

// Round 7
// 137.066 us; speedup vs baseline: 2.6465x; 1.0208x over previous
//
#include <hip/hip_runtime.h>
#include <cstdint>
#include <cstddef>

#define S_CELLS 4096   // 64*64
#define NB      8
#define NPTS    8192
#define E       128
#define MAXP    20
#define NHEADS  8
#define NPT_ROWS 65536
#define NGR_ROWS 32768

// ws layout (bytes):
#define WS_COUNTS 0          // int[32768]        (131072)
#define WS_SLOTS  131072     // int[32768*20]     (2621440)
#define WS_WT1    2752512    // bf16 144x136      (40960 w/ pad)
#define WS_WT2    2793472    // bf16 128x136      (34816)
#define WS_SC     2828288    // float[98304*8]    (3145728)
#define WS_V      5974016    // bf16[98304*128]   (25165824)

typedef __attribute__((ext_vector_type(8))) short bf16x8;
typedef __attribute__((ext_vector_type(4))) float f32x4;

__device__ __forceinline__ unsigned short f2bf_bits(float f) {   // RNE (cold paths)
    unsigned u = __float_as_uint(f);
    unsigned rounded = u + 0x7FFFu + ((u >> 16) & 1u);
    return (unsigned short)(rounded >> 16);
}
__device__ __forceinline__ unsigned short f2bf_rta(float f) {    // round-ties-away (hot)
    return (unsigned short)((__float_as_uint(f) + 0x8000u) >> 16);
}
__device__ __forceinline__ unsigned pack_bf2(float a, float b) { // [b|a] packed bf16
    unsigned ua = __float_as_uint(a) + 0x8000u;
    unsigned ub = __float_as_uint(b) + 0x8000u;
    return (ua >> 16) | (ub & 0xFFFF0000u);
}
__device__ __forceinline__ float bf2f(unsigned short u) {
    return __uint_as_float(((unsigned)u) << 16);
}

// ---------------------------------------------------------------------------
// Kernel 1 (9 blocks x 256): zero counts (striped) +
//   block 0    : q = latent@Wq; A[i][h]=(Wk[i,h*16:+16].q_h)/4 -> WT1 rows
//                128..135; zero rows 136..143
//   blocks 1..4: Wv -> WT1 rows 0..127 (bf16, transposed [n][k], stride 136)
//   blocks 5..8: Wo -> WT2 (same layout)
// ---------------------------------------------------------------------------
__global__ void __launch_bounds__(256)
k_prep(const float* __restrict__ latent,
       const float* __restrict__ Wq,
       const float* __restrict__ Wk,
       const float* __restrict__ Wv,
       const float* __restrict__ Wo,
       int* __restrict__ counts,
       unsigned short* __restrict__ WT1,
       unsigned short* __restrict__ WT2) {
    const int t   = threadIdx.x;
    const int blk = blockIdx.x;

    {   // zero counts: 8192 int4s across 9*256 threads
        int4* c4 = (int4*)counts;
        for (int idx = blk * 256 + t; idx < 8192; idx += 9 * 256)
            c4[idx] = int4{0, 0, 0, 0};
    }

    if (blk == 0) {
        __shared__ float lat[E];
        __shared__ float qv[E];
        const int j = t & 127;
        if (t < E) lat[t] = latent[t];
        __syncthreads();
        float acc = 0.0f;                    // both halves compute identical q[j]
        for (int k2 = 0; k2 < E; ++k2) acc += lat[k2] * Wq[k2 * E + j];
        qv[j] = acc;
        __syncthreads();
        const int hb = (t >> 7) * 4;
        for (int h = hb; h < hb + 4; ++h) {
            float a = 0.0f;
            #pragma unroll
            for (int d = 0; d < 16; ++d) a += Wk[j * E + h * 16 + d] * qv[h * 16 + d];
            WT1[(size_t)(128 + h) * 136 + j] = f2bf_bits(a * 0.25f);
        }
        for (int idx = t; idx < 8 * 136; idx += 256) {   // zero rows 136..143
            int rr = idx / 136, cc = idx - rr * 136;
            WT1[(size_t)(136 + rr) * 136 + cc] = 0;
        }
        return;
    }

    // weight conversion: transpose via LDS, coalesced in and out
    const float* W = (blk < 5) ? Wv : Wo;
    unsigned short* WT = (blk < 5) ? WT1 : WT2;
    const int n0 = ((blk - 1) & 3) * 32;
    __shared__ float lbuf[128][33];
    #pragma unroll
    for (int it = 0; it < 16; ++it) {
        int k  = (t >> 5) + it * 8;
        int nl = t & 31;
        lbuf[k][nl] = W[(size_t)k * E + n0 + nl];
    }
    __syncthreads();
    for (int idx = t; idx < 32 * 136; idx += 256) {
        int nl = idx / 136, k = idx - nl * 136;
        float v = (k < 128) ? lbuf[k][nl] : 0.0f;
        WT[(size_t)(n0 + nl) * 136 + k] = f2bf_bits(v);
    }
}

// ---------------------------------------------------------------------------
// Kernel 2 (1024 blocks x 256):
//   blocks 0..767  : MFMA GEMM  V = [z; z_grid] @ Wv (bf16) + SC = X @ A
//   blocks 768..1023: per-point binning + x_grid passthrough copy
//     (independent of GEMM; hidden behind it. counts pre-zeroed by k_prep.)
// GEMM: WT1 image staged by linear float4 copy; 4 waves x MT=2 = 128 rows/blk.
// Layouts (HW-verified): A-frag m=lane&15, k=kq*32+q*8+j; B-frag n=lane&15
// same k; C/D col=lane&15, row=q*4+r.
// ---------------------------------------------------------------------------
__device__ __forceinline__ bf16x8 load_afrag_f32(const float* __restrict__ X,
                                                 int row, int kq, int q) {
    const float4* xr = (const float4*)(X + (size_t)row * E);
    float4 lo = xr[kq * 8 + q * 2];
    float4 hi = xr[kq * 8 + q * 2 + 1];
    unsigned u[4];
    u[0] = pack_bf2(lo.x, lo.y);
    u[1] = pack_bf2(lo.z, lo.w);
    u[2] = pack_bf2(hi.x, hi.y);
    u[3] = pack_bf2(hi.z, hi.w);
    union { unsigned u4[4]; bf16x8 v; } cv;
    cv.u4[0] = u[0]; cv.u4[1] = u[1]; cv.u4[2] = u[2]; cv.u4[3] = u[3];
    return cv.v;
}

__global__ void __launch_bounds__(256)
k_main(const float* __restrict__ x,
       const float* __restrict__ x_grid,
       const float* __restrict__ Xz,
       const float* __restrict__ Xg,
       const unsigned short* __restrict__ WT1g,
       int* __restrict__ counts,
       int* __restrict__ slots,
       unsigned short* __restrict__ V,
       float* __restrict__ SC,
       float* __restrict__ out_xgrid) {
    __shared__ unsigned short W_t[20480];    // 40960 B

    const int t = threadIdx.x;

    if (blockIdx.x >= 768) {                 // ---- binning + x_grid copy
        int i = (blockIdx.x - 768) * 256 + t;   // 0..65535
        out_xgrid[i] = x_grid[i];
        int b = i >> 13;
        float x0 = x[(size_t)i * 2 + 0];
        float x1 = x[(size_t)i * 2 + 1];
        int i0 = (int)rintf(x0 * 63.0f);     // RNE matches jnp.round
        int i1 = (int)rintf(x1 * 63.0f);
        i0 = min(max(i0, 0), 63);
        i1 = min(max(i1, 0), 63);
        int cell = b * S_CELLS + i0 * 64 + i1;
        int slot = atomicAdd(&counts[cell], 1);
        if (slot < MAXP) slots[(size_t)cell * MAXP + slot] = i & (NPTS - 1);
        return;
    }

    {   // linear stage of WT1 image (no transpose -> no conflicts)
        const float4* src = (const float4*)WT1g;
        float4* dst = (float4*)W_t;
        #pragma unroll
        for (int it = 0; it < 10; ++it) dst[t + it * 256] = src[t + it * 256];
    }
    __syncthreads();

    const int lane = t & 63;
    const int wv   = t >> 6;
    const int cn   = lane & 15;
    const int q    = lane >> 4;

    const int grow0 = blockIdx.x * 128;
    const float* Xsrc;
    int srow;
    if (blockIdx.x < 512) { Xsrc = Xz; srow = grow0; }
    else                  { Xsrc = Xg; srow = grow0 - NPT_ROWS; }

    f32x4 acc[2][9];
    #pragma unroll
    for (int mt = 0; mt < 2; ++mt)
        #pragma unroll
        for (int nt = 0; nt < 9; ++nt)
            acc[mt][nt] = f32x4{0.0f, 0.0f, 0.0f, 0.0f};

    #pragma unroll
    for (int kq = 0; kq < 4; ++kq) {
        bf16x8 a[2];
        #pragma unroll
        for (int mt = 0; mt < 2; ++mt)
            a[mt] = load_afrag_f32(Xsrc, srow + wv * 32 + mt * 16 + cn, kq, q);
        #pragma unroll
        for (int nt = 0; nt < 9; ++nt) {
            const bf16x8 b = *(const bf16x8*)&W_t[(size_t)(nt * 16 + cn) * 136 + kq * 32 + q * 8];
            #pragma unroll
            for (int mt = 0; mt < 2; ++mt)
                acc[mt][nt] = __builtin_amdgcn_mfma_f32_16x16x32_bf16(
                    a[mt], b, acc[mt][nt], 0, 0, 0);
        }
    }

    #pragma unroll
    for (int mt = 0; mt < 2; ++mt) {
        const int rb = grow0 + wv * 32 + mt * 16 + q * 4;
        #pragma unroll
        for (int nt = 0; nt < 8; ++nt)
            #pragma unroll
            for (int r = 0; r < 4; ++r)
                V[(size_t)(rb + r) * E + nt * 16 + cn] = f2bf_rta(acc[mt][nt][r]);
        if (cn < 8) {
            #pragma unroll
            for (int r = 0; r < 4; ++r)
                SC[(size_t)(rb + r) * NHEADS + cn] = acc[mt][8][r];
        }
    }
}

// ---------------------------------------------------------------------------
// Kernel 3 (2048 blocks x 1024): fused attention + Wo projection.
//   Block = 16 cells, 16 waves; wave wv gathers cell cb+wv (1 cell/wave ->
//   minimal serial depth). Lane owns cols {2l,2l+1} (head h=l>>3 -> one
//   softmax state, packed uint V loads). Result -> X_s[wv] (bf16,
//   A-frag-ready). Phase 2: waves 0..7 hold Wo B-frags for nt=wv in
//   REGISTERS (preloaded, coalesced) -> 4 MFMAs each; no Wo LDS staging.
// LDS: 4352 B only.
// ---------------------------------------------------------------------------
__global__ void __launch_bounds__(1024)
k_attn_proj(const int* __restrict__ counts,
            const int* __restrict__ slots,
            const float* __restrict__ SC,
            const unsigned short* __restrict__ Vg,
            const unsigned short* __restrict__ WT2g,
            float* __restrict__ zg) {
    __shared__ __align__(16) unsigned short X_s[16][136];

    const int t    = threadIdx.x;
    const int lane = t & 63;
    const int wv   = t >> 6;                 // 0..15
    const int cb   = blockIdx.x * 16;
    const int b    = cb >> 12;
    const int base = b * NPTS;
    const int cn   = lane & 15;
    const int q    = lane >> 4;

    // preload Wo B-fragments (nt = wv for waves 0..7) — independent of phase 1
    bf16x8 bfr[4];
    if (wv < 8) {
        #pragma unroll
        for (int kq = 0; kq < 4; ++kq)
            bfr[kq] = *(const bf16x8*)&WT2g[(size_t)(wv * 16 + cn) * 136 + kq * 32 + q * 8];
    }

    // ---- phase 1: gather + online softmax for cell cb+wv
    const int cell = cb + wv;
    const int m    = min(counts[cell], MAXP);          // wave-uniform broadcast
    int sl = (lane < MAXP) ? slots[(size_t)cell * MAXP + lane] : 0;
    const int h = lane >> 3;

    size_t r0 = (size_t)(NPT_ROWS + cell);
    float mm = SC[r0 * NHEADS + h];
    float ss = 1.0f;
    unsigned v0 = *(const unsigned*)(Vg + r0 * E + 2 * lane);
    float o0 = bf2f((unsigned short)v0);
    float o1 = bf2f((unsigned short)(v0 >> 16));

    for (int t0 = 0; t0 < m; t0 += 4) {
        float av[4], p0[4], p1[4];
        #pragma unroll
        for (int j = 0; j < 4; ++j) {
            int pt = __shfl(sl, t0 + j, 64);
            bool val = (t0 + j) < m;
            pt = val ? pt : 0;               // slots beyond m are garbage
            size_t r = (size_t)(base + pt);
            float sa = SC[r * NHEADS + h];
            av[j] = val ? sa : -1e30f;       // masked -> e=0, alpha=1: exact no-op
            unsigned vv = *(const unsigned*)(Vg + r * E + 2 * lane);
            p0[j] = bf2f((unsigned short)vv);
            p1[j] = bf2f((unsigned short)(vv >> 16));
        }
        #pragma unroll
        for (int j = 0; j < 4; ++j) {
            float nm = fmaxf(mm, av[j]);
            float e  = __expf(av[j] - nm);
            float al = __expf(mm - nm);
            ss = ss * al + e;
            o0 = o0 * al + e * p0[j];
            o1 = o1 * al + e * p1[j];
            mm = nm;
        }
    }
    float inv = 1.0f / ss;
    *(unsigned*)&X_s[wv][2 * lane] = pack_bf2(o0 * inv, o1 * inv);
    __syncthreads();

    // ---- phase 2: zg[cb..cb+15][:] = X_s @ Wo  (wave wv -> col tile nt=wv)
    if (wv < 8) {
        f32x4 acc = f32x4{0.0f, 0.0f, 0.0f, 0.0f};
        #pragma unroll
        for (int kq = 0; kq < 4; ++kq) {
            bf16x8 a = *(const bf16x8*)&X_s[cn][kq * 32 + q * 8];
            acc = __builtin_amdgcn_mfma_f32_16x16x32_bf16(a, bfr[kq], acc, 0, 0, 0);
        }
        #pragma unroll
        for (int r = 0; r < 4; ++r)
            zg[(size_t)(cb + q * 4 + r) * E + wv * 16 + cn] = acc[r];
    }
}

// ---------------------------------------------------------------------------
extern "C" void kernel_launch(void* const* d_in, const int* in_sizes, int n_in,
                              void* d_out, int out_size, void* d_ws, size_t ws_size,
                              hipStream_t stream) {
    const float* x      = (const float*)d_in[0];
    const float* z      = (const float*)d_in[1];
    const float* x_grid = (const float*)d_in[2];
    const float* z_grid = (const float*)d_in[3];
    const float* latent = (const float*)d_in[4];
    const float* Wq     = (const float*)d_in[5];
    const float* Wk     = (const float*)d_in[6];
    const float* Wv     = (const float*)d_in[7];
    const float* Wo     = (const float*)d_in[8];

    char* ws = (char*)d_ws;
    int*            counts = (int*)(ws + WS_COUNTS);
    int*            slots  = (int*)(ws + WS_SLOTS);
    unsigned short* WT1    = (unsigned short*)(ws + WS_WT1);
    unsigned short* WT2    = (unsigned short*)(ws + WS_WT2);
    float*          SC     = (float*)(ws + WS_SC);
    unsigned short* V      = (unsigned short*)(ws + WS_V);

    float* out_xgrid = (float*)d_out;                  // 65536 floats
    float* zg        = (float*)d_out + NB * NPTS;      // 32768*128 floats

    k_prep<<<9, 256, 0, stream>>>(latent, Wq, Wk, Wv, Wo, counts, WT1, WT2);

    k_main<<<1024, 256, 0, stream>>>(x, x_grid, z, z_grid, WT1,
                                     counts, slots, V, SC, out_xgrid);

    k_attn_proj<<<2048, 1024, 0, stream>>>(counts, slots, SC, V, WT2, zg);
}